// Round 8
// baseline (458.839 us; speedup 1.0000x reference)
//
#include <hip/hip_runtime.h>
#include <hip/hip_fp16.h>
#include <math.h>

#define N_NODES 262144
#define N_EDGES 4194304
#define N_GRAPHS 1024
#define NBK 1024                 // dst buckets (256 nodes each)
#define CAP 5120                 // per-bucket capacity (mean 4096, +16 sigma)
#define ABLK 512                 // fusedAB blocks
#define AEPB (N_EDGES / ABLK)    // 8192 edges per block

typedef _Float16 half2v __attribute__((ext_vector_type(2)));
__device__ inline half2v u2h(unsigned u) { union { unsigned u; half2v h; } c; c.u = u; return c.h; }
__device__ inline unsigned packh2(float a, float b) {
    union { __half2 h; unsigned u; } c; c.h = __floats2half2_rn(a, b); return c.u;
}
__device__ inline float2 h2f(unsigned u) { __half2 h = *(__half2*)&u; return __half22float2(h); }

// ---------------------------------------------------------------------------
// fusedAB: pack px16 + zero pooled + per-block bucket hist + global range
// reservation (padded cursors, 1 line each) + line-dense binned scatter.
// Replaces passA + scan1/2/3 + passB + pack (order within bucket is
// irrelevant: downstream aggregation is a commutative sum).
// ---------------------------------------------------------------------------
__global__ __launch_bounds__(256) void fusedAB(
    const int* __restrict__ ei, const float* __restrict__ x,
    const float* __restrict__ pos, int* __restrict__ gcur,
    int* __restrict__ binned, uint4* __restrict__ px16,
    float* __restrict__ pooled)
{
    __shared__ int lh[NBK];
    int t = threadIdx.x, b = blockIdx.x;

    // pack 2 nodes per thread (fp16 x4 + pos3 -> one 16B record, 4MB total)
    #pragma unroll
    for (int k = 0; k < 2; ++k) {
        int n = b * 512 + k * 256 + t;
        float4 v = ((const float4*)x)[n];
        float p0 = pos[3 * n], p1 = pos[3 * n + 1], p2 = pos[3 * n + 2];
        uint4 r;
        r.x = packh2(v.x, v.y);
        r.y = packh2(v.z, v.w);
        r.z = packh2(p0, p1);
        r.w = packh2(p2, 0.0f);
        px16[n] = r;
    }
    int pid = b * 256 + t;
    if (pid < N_GRAPHS * 32) pooled[pid] = 0.0f;

    #pragma unroll
    for (int k = 0; k < 4; ++k) lh[t + 256 * k] = 0;
    __syncthreads();

    int base = b * AEPB;
    for (int i = 0; i < AEPB / 256; ++i) {
        int d = ei[N_EDGES + base + i * 256 + t];
        atomicAdd(&lh[d >> 8], 1);
    }
    __syncthreads();
    #pragma unroll
    for (int k = 0; k < 4; ++k) {
        int kb = t + 256 * k;
        lh[kb] = atomicAdd(&gcur[kb * 16], lh[kb]);   // reserve contiguous range
    }
    __syncthreads();
    for (int i = 0; i < AEPB / 256; ++i) {
        int e = base + i * 256 + t;
        int s = ei[e];
        int d = ei[N_EDGES + e];
        int slot = atomicAdd(&lh[d >> 8], 1);
        if (slot < CAP)
            binned[(size_t)(d >> 8) * CAP + slot] = s | ((d & 255) << 18);
    }
}

// ---------------------------------------------------------------------------
// bucket_fused: one block per 256-node bucket. Edge-per-thread MLP (all 64
// lanes on distinct edges), LDS f32 atomic accumulation (stride-17 rows ->
// bank-spread), then per-node W2/mean/relu/softmax + graph-segmented pooling.
// Replaces passC + node_gather_fused.
// ---------------------------------------------------------------------------
__global__ __launch_bounds__(256, 4) void bucket_fused(
    const int* __restrict__ binned, const int* __restrict__ gcur,
    const uint4* __restrict__ px16,
    const float* __restrict__ W1, const float* __restrict__ b1,
    const float* __restrict__ W2, const float* __restrict__ b2,
    const float* __restrict__ Wp, const float* __restrict__ bp,
    const int* __restrict__ batch,
    float* __restrict__ out_s, float* __restrict__ pooled)
{
    __shared__ unsigned drec[256][6];   // x01,x23,pos01,posz (stride 6: b64-aligned)
    __shared__ float acc[256][17];      // 16 sums + edge count (17: bank-spread)
    __shared__ float2 sst[256];
    __shared__ float lpool[8][33];
    __shared__ int bloc[256];

    int t = threadIdx.x, k = blockIdx.x;
    int n0 = k * 256;

    uint4 rn = px16[n0 + t];
    drec[t][0] = rn.x; drec[t][1] = rn.y; drec[t][2] = rn.z; drec[t][3] = rn.w;
    #pragma unroll
    for (int c = 0; c < 17; ++c) acc[t][c] = 0.0f;
    bloc[t] = batch[n0 + t];
    for (int i = t; i < 8 * 33; i += 256) ((float*)lpool)[i] = 0.0f;

    // W1 columns in registers (fp16 pairs), b1 fused with w8
    unsigned w01[16], w23[16], w45[16], w67[16], w8b1[16];
    #pragma unroll
    for (int c = 0; c < 16; ++c) {
        w01[c]  = packh2(W1[c],       W1[16 + c]);
        w23[c]  = packh2(W1[32 + c],  W1[48 + c]);
        w45[c]  = packh2(W1[64 + c],  W1[80 + c]);
        w67[c]  = packh2(W1[96 + c],  W1[112 + c]);
        w8b1[c] = packh2(W1[128 + c], b1[c]);
    }
    int cnt = gcur[k * 16];
    if (cnt > CAP) cnt = CAP;
    __syncthreads();

    size_t ebase = (size_t)k * CAP;
    // 2-deep pipelined edge loop
    unsigned pkC = 0, pkN = 0;
    if (t < cnt) pkC = binned[ebase + t];
    uint4 rsC = px16[pkC & 0x3FFFF];
    if (t + 256 < cnt) pkN = binned[ebase + t + 256];

    for (int i = t; i < cnt; i += 256) {
        uint4 rsN = px16[pkN & 0x3FFFF];
        unsigned pkNN = 0;
        if (i + 512 < cnt) pkNN = binned[ebase + i + 512];

        int dl = pkC >> 18;
        uint2 dxa = *(uint2*)&drec[dl][0];
        uint2 dpp = *(uint2*)&drec[dl][2];
        float2 sp = h2f(rsC.z); float spz = h2f(rsC.w).x;
        float2 dp = h2f(dpp.x); float dpz = h2f(dpp.y).x;
        float dx = sp.x - dp.x, dy = sp.y - dp.y, dz = spz - dpz;
        float dist = sqrtf(dx * dx + dy * dy + dz * dz);
        unsigned d1 = packh2(dist, 1.0f);

        #pragma unroll
        for (int c = 0; c < 16; ++c) {
            float a = __builtin_amdgcn_fdot2(u2h(dxa.x), u2h(w01[c]),
                      __builtin_amdgcn_fdot2(u2h(dxa.y), u2h(w23[c]),
                      __builtin_amdgcn_fdot2(u2h(rsC.x), u2h(w45[c]),
                      __builtin_amdgcn_fdot2(u2h(rsC.y), u2h(w67[c]),
                      __builtin_amdgcn_fdot2(u2h(d1),    u2h(w8b1[c]),
                                             0.0f, false), false), false), false), false);
            float hv = a * __builtin_amdgcn_rcpf(1.0f + __expf(-a));  // silu
            atomicAdd(&acc[dl][c], hv);
        }
        atomicAdd(&acc[dl][16], 1.0f);

        pkC = pkN; rsC = rsN; pkN = pkNN;
    }
    __syncthreads();

    // per-node epilogue: W2 (scalar loads), mean, relu, softmax gate
    float hs[16];
    #pragma unroll
    for (int i = 0; i < 16; ++i) hs[i] = acc[t][i];
    float deg = acc[t][16];
    float inv = 1.0f / fmaxf(deg, 1.0f);
    float h[16];
    #pragma unroll
    for (int co = 0; co < 16; ++co) {
        float m = deg * b2[co];
        #pragma unroll
        for (int i = 0; i < 16; ++i) m = fmaf(hs[i], W2[i * 16 + co], m);
        h[co] = fmaxf(m * inv, 0.0f);
    }
    float l0 = bp[0], l1 = bp[1];
    #pragma unroll
    for (int c = 0; c < 16; ++c) {
        l0 = fmaf(h[c], Wp[2 * c], l0);
        l1 = fmaf(h[c], Wp[2 * c + 1], l1);
    }
    float mx = fmaxf(l0, l1);
    float e0 = __expf(l0 - mx), e1 = __expf(l1 - mx);
    float is = 1.0f / (e0 + e1);
    float s0 = e0 * is, s1 = e1 * is;
    ((float2*)out_s)[n0 + t] = make_float2(s0, s1);

    #pragma unroll
    for (int c = 0; c < 16; ++c) acc[t][c] = h[c];
    sst[t] = make_float2(s0, s1);
    __syncthreads();

    // graph-segmented pooling (bucket spans ~2-4 graphs; batch sorted)
    int g0 = bloc[0], gN = bloc[255];
    int ngr = gN - g0 + 1;
    if (ngr <= 8) {
        int c = t & 31, chunk = t >> 5;
        for (int gi = 0; gi < ngr; ++gi) {
            int gid = g0 + gi;
            int lo = 0, hi = 256;
            while (lo < hi) { int m = (lo + hi) >> 1; if (bloc[m] < gid) lo = m + 1; else hi = m; }
            int a = lo, bnd = 256;
            while (a < bnd) { int m = (a + bnd) >> 1; if (bloc[m] < gid + 1) a = m + 1; else bnd = m; }
            float part = 0.0f;
            for (int n = lo + chunk; n < a; n += 8) {
                float2 sv = sst[n];
                part += (c < 16 ? sv.x : sv.y) * acc[n][c & 15];
            }
            if (part != 0.0f) atomicAdd(&lpool[gi][c], part);
        }
        __syncthreads();
        for (int i = t; i < ngr * 32; i += 256)
            atomicAdd(&pooled[(g0 + i / 32) * 32 + (i & 31)], lpool[i / 32][i & 31]);
    } else {  // pathological many-tiny-graphs fallback
        int gid = bloc[t];
        #pragma unroll
        for (int c = 0; c < 16; ++c) {
            atomicAdd(&pooled[gid * 32 + c],      sst[t].x * acc[t][c]);
            atomicAdd(&pooled[gid * 32 + 16 + c], sst[t].y * acc[t][c]);
        }
    }
}

// ---------------------------------------------------------------------------
// z = pooled.reshape(G,32) @ Wz + bz
// ---------------------------------------------------------------------------
__global__ __launch_bounds__(256) void z_kernel(const float* __restrict__ pooled,
                                                const float* __restrict__ Wz,
                                                const float* __restrict__ bz,
                                                float* __restrict__ out_z) {
    int idx = blockIdx.x * 256 + threadIdx.x;
    if (idx >= N_GRAPHS * 8) return;
    int gph = idx >> 3, o = idx & 7;
    float a = bz[o];
    const float* pp = pooled + (size_t)gph * 32;
    #pragma unroll
    for (int j = 0; j < 32; ++j) a = fmaf(pp[j], Wz[j * 8 + o], a);
    out_z[idx] = a;
}

extern "C" void kernel_launch(void* const* d_in, const int* in_sizes, int n_in,
                              void* d_out, int out_size, void* d_ws, size_t ws_size,
                              hipStream_t stream) {
    const float* x    = (const float*)d_in[0];
    const float* pos  = (const float*)d_in[1];
    const float* W1   = (const float*)d_in[2];
    const float* b1   = (const float*)d_in[3];
    const float* W2   = (const float*)d_in[4];
    const float* b2   = (const float*)d_in[5];
    const float* Wp   = (const float*)d_in[6];
    const float* bp   = (const float*)d_in[7];
    const float* Wz   = (const float*)d_in[8];
    const float* bz   = (const float*)d_in[9];
    const int*   ei   = (const int*)d_in[10];
    const int*   batch= (const int*)d_in[11];
    float* out = (float*)d_out;
    float* out_z = out;                   // [1024*8]
    float* out_s = out + N_GRAPHS * 8;    // [262144*2]

    // ws layout (ints): gcur[1024*16 padded] | binned[1024*CAP] | px16[N uint4] | pooled
    int* gcur     = (int*)d_ws;
    int* binned   = gcur + NBK * 16;
    uint4* px16   = (uint4*)(binned + (size_t)NBK * CAP);   // 16B-aligned offset
    float* pooled = (float*)(px16 + N_NODES);

    hipMemsetAsync(gcur, 0, NBK * 16 * sizeof(int), stream);
    fusedAB<<<ABLK, 256, 0, stream>>>(ei, x, pos, gcur, binned, px16, pooled);
    bucket_fused<<<NBK, 256, 0, stream>>>(binned, gcur, px16, W1, b1, W2, b2,
                                          Wp, bp, batch, out_s, pooled);
    z_kernel<<<32, 256, 0, stream>>>(pooled, Wz, bz, out_z);
}

// Round 9
// 199.360 us; speedup vs baseline: 2.3016x; 2.3016x over previous
//
#include <hip/hip_runtime.h>
#include <hip/hip_fp16.h>
#include <math.h>

#define N_NODES 262144
#define N_EDGES 4194304
#define N_GRAPHS 1024
#define NBK 1024                 // dst buckets (256 nodes each)
#define CAP 5120                 // per-bucket capacity (mean 4096, +16 sigma)
#define ABLK 512                 // fusedAB blocks
#define AEPB (N_EDGES / ABLK)    // 8192 edges per block

typedef _Float16 half2v __attribute__((ext_vector_type(2)));
__device__ inline half2v u2h(unsigned u) { union { unsigned u; half2v h; } c; c.u = u; return c.h; }
__device__ inline unsigned packh2(float a, float b) {
    union { __half2 h; unsigned u; } c; c.h = __floats2half2_rn(a, b); return c.u;
}

// ---------------------------------------------------------------------------
// fusedAB: pack px16 + zero pooled + per-block bucket hist + global range
// reservation (padded cursors) + line-dense binned scatter of
// (src | dstlow<<18) into the bucket's fixed-capacity region.
// Replaces passA + scan1/2/3 + passB + pack. (Order within bucket is
// irrelevant: downstream aggregation is a commutative sum.)   [R8-verified]
// ---------------------------------------------------------------------------
__global__ __launch_bounds__(256) void fusedAB(
    const int* __restrict__ ei, const float* __restrict__ x,
    const float* __restrict__ pos, int* __restrict__ gcur,
    int* __restrict__ binned, uint4* __restrict__ px16,
    float* __restrict__ pooled)
{
    __shared__ int lh[NBK];
    int t = threadIdx.x, b = blockIdx.x;

    // pack 2 nodes per thread (fp16 x4 + pos3 -> one 16B record, 4MB total)
    #pragma unroll
    for (int k = 0; k < 2; ++k) {
        int n = b * 512 + k * 256 + t;
        float4 v = ((const float4*)x)[n];
        float p0 = pos[3 * n], p1 = pos[3 * n + 1], p2 = pos[3 * n + 2];
        uint4 r;
        r.x = packh2(v.x, v.y);
        r.y = packh2(v.z, v.w);
        r.z = packh2(p0, p1);
        r.w = packh2(p2, 0.0f);
        px16[n] = r;
    }
    int pid = b * 256 + t;
    if (pid < N_GRAPHS * 32) pooled[pid] = 0.0f;

    #pragma unroll
    for (int k = 0; k < 4; ++k) lh[t + 256 * k] = 0;
    __syncthreads();

    int base = b * AEPB;
    for (int i = 0; i < AEPB / 256; ++i) {
        int d = ei[N_EDGES + base + i * 256 + t];
        atomicAdd(&lh[d >> 8], 1);
    }
    __syncthreads();
    #pragma unroll
    for (int k = 0; k < 4; ++k) {
        int kb = t + 256 * k;
        lh[kb] = atomicAdd(&gcur[kb * 16], lh[kb]);   // reserve contiguous range
    }
    __syncthreads();
    for (int i = 0; i < AEPB / 256; ++i) {
        int e = base + i * 256 + t;
        int s = ei[e];
        int d = ei[N_EDGES + e];
        int slot = atomicAdd(&lh[d >> 8], 1);
        if (slot < CAP)
            binned[(size_t)(d >> 8) * CAP + slot] = s | ((d & 255) << 18);
    }
}

// ---------------------------------------------------------------------------
// passC: per-bucket node sort, in place. Stage bucket edges in LDS, per-node
// deg + Hillis-Steele scan, then rewrite the SAME binned region in
// node-grouped order holding only src ids. srcs aliases binned afterward.
// startg[n] = bucketBase + excl (absolute index).
// ---------------------------------------------------------------------------
__global__ __launch_bounds__(256) void passC_sort(
    const int* __restrict__ gcur,
    int* __restrict__ binned,
    int* __restrict__ startg, int* __restrict__ degg)
{
    __shared__ int lbuf[CAP];
    __shared__ int ldeg[256], sc2[256], lcur[256];
    int t = threadIdx.x, k = blockIdx.x;
    int ebase = k * CAP;
    int cnt = gcur[k * 16];
    if (cnt > CAP) cnt = CAP;

    ldeg[t] = 0;
    __syncthreads();
    for (int i = t; i < cnt; i += 256) {
        int pk = binned[ebase + i];
        lbuf[i] = pk;
        atomicAdd(&ldeg[pk >> 18], 1);
    }
    __syncthreads();
    sc2[t] = ldeg[t];
    __syncthreads();
    for (int o = 1; o < 256; o <<= 1) {
        int u = (t >= o) ? sc2[t - o] : 0;
        __syncthreads();
        sc2[t] += u;
        __syncthreads();
    }
    int excl = sc2[t] - ldeg[t];
    int n = k * 256 + t;
    startg[n] = ebase + excl;
    degg[n] = ldeg[t];
    lcur[t] = excl;
    __syncthreads();
    for (int i = t; i < cnt; i += 256) {
        int pk = lbuf[i];
        int slot = atomicAdd(&lcur[pk >> 18], 1);
        binned[ebase + slot] = pk & 0x3FFFF;
    }
}

// ---------------------------------------------------------------------------
// Gather + edge MLP (R7-verified, byte-identical). Inner loop: 1 ds_read_b128
// per edge + 2 v_dot2_f32_f16 + exp chain. W2 applied once per node via LDS
// transpose of sumH. Fused per-graph pooling.
// ---------------------------------------------------------------------------
__global__ __launch_bounds__(256) void node_gather_fused(
    const uint4* __restrict__ px16,
    const int* __restrict__ srcs, const int* __restrict__ startg,
    const int* __restrict__ degg,
    const float* __restrict__ W1, const float* __restrict__ b1,
    const float* __restrict__ W2, const float* __restrict__ b2,
    const float* __restrict__ Wp, const float* __restrict__ bp,
    const int* __restrict__ batch,
    float* __restrict__ out_s, float* __restrict__ pooled)
{
    __shared__ uint4 sepk[16][17];   // staged edges: {x01,x23,dist,pad}
    __shared__ float smh[16][20];    // sumH transpose (padded rows)

    int t = threadIdx.x;
    int g = t & 15;
    int grp = t >> 4;
    int n = blockIdx.x * 16 + grp;

    // per-lane weights (registers)
    float w1c0 = W1[0 * 16 + g], w1c1 = W1[1 * 16 + g];
    float w1c2 = W1[2 * 16 + g], w1c3 = W1[3 * 16 + g];
    half2v wh45, wh67;
    wh45[0] = (_Float16)W1[4 * 16 + g];
    wh45[1] = (_Float16)W1[5 * 16 + g];
    wh67[0] = (_Float16)W1[6 * 16 + g];
    wh67[1] = (_Float16)W1[7 * 16 + g];
    float w1c8 = W1[8 * 16 + g];
    float b1g = b1[g], b2g = b2[g];
    float w2col[16];
    #pragma unroll
    for (int i = 0; i < 16; ++i) w2col[i] = W2[i * 16 + g];  // column g
    float wp0 = Wp[2 * g], wp1 = Wp[2 * g + 1];

    int base = startg[n];
    int dg = degg[n];

    // self record
    uint4 rn = px16[n];
    float2 f01 = __half22float2(*(__half2*)&rn.x);
    float2 f23 = __half22float2(*(__half2*)&rn.y);
    float2 f45 = __half22float2(*(__half2*)&rn.z);
    float2 f67 = __half22float2(*(__half2*)&rn.w);
    float pnx = f45.x, pny = f45.y, pnz = f67.x;
    float pre = b1g + f01.x * w1c0 + f01.y * w1c1 + f23.x * w1c2 + f23.y * w1c3;

    float sumH = 0.0f;

    // pipeline prologue
    int sC = 0;
    if (g < dg) sC = srcs[base + g];
    uint4 rC = px16[sC];
    int sN = sC;
    if (16 + g < dg) sN = srcs[base + 16 + g];

    for (int k0 = 0; k0 < dg; k0 += 16) {
        int rem = dg - k0;
        int cnt = rem < 16 ? rem : 16;
        if (g < cnt) {
            float2 e45 = __half22float2(*(__half2*)&rC.z);
            float2 e67 = __half22float2(*(__half2*)&rC.w);
            float dx = e45.x - pnx, dy = e45.y - pny, dz = e67.x - pnz;
            float dist = sqrtf(dx * dx + dy * dy + dz * dz);
            sepk[grp][g] = make_uint4(rC.x, rC.y, __float_as_uint(dist), 0u);
        }
        // issue next chunk's loads
        uint4 rNext = px16[sN];
        int sNN = sN;
        if (k0 + 32 + g < dg) sNN = srcs[base + k0 + 32 + g];
        // compute current chunk from LDS (2x unrolled to batch waits)
        int j = 0;
        for (; j + 1 < cnt; j += 2) {
            uint4 A = sepk[grp][j];
            uint4 B = sepk[grp][j + 1];
            float a = fmaf(__uint_as_float(A.z), w1c8, pre);
            a = __builtin_amdgcn_fdot2(u2h(A.x), wh45, a, false);
            a = __builtin_amdgcn_fdot2(u2h(A.y), wh67, a, false);
            sumH += a * __builtin_amdgcn_rcpf(1.0f + __expf(-a));
            float b = fmaf(__uint_as_float(B.z), w1c8, pre);
            b = __builtin_amdgcn_fdot2(u2h(B.x), wh45, b, false);
            b = __builtin_amdgcn_fdot2(u2h(B.y), wh67, b, false);
            sumH += b * __builtin_amdgcn_rcpf(1.0f + __expf(-b));
        }
        if (j < cnt) {
            uint4 A = sepk[grp][j];
            float a = fmaf(__uint_as_float(A.z), w1c8, pre);
            a = __builtin_amdgcn_fdot2(u2h(A.x), wh45, a, false);
            a = __builtin_amdgcn_fdot2(u2h(A.y), wh67, a, false);
            sumH += a * __builtin_amdgcn_rcpf(1.0f + __expf(-a));
        }
        rC = rNext;
        sN = sNN;
    }

    // LDS-transpose epilogue: lane g applies W2 column g.
    smh[grp][g] = sumH;
    float4 s0v = *(const float4*)&smh[grp][0];
    float4 s1v = *(const float4*)&smh[grp][4];
    float4 s2v = *(const float4*)&smh[grp][8];
    float4 s3v = *(const float4*)&smh[grp][12];
    float red = s0v.x * w2col[0] + s0v.y * w2col[1] + s0v.z * w2col[2] + s0v.w * w2col[3]
              + s1v.x * w2col[4] + s1v.y * w2col[5] + s1v.z * w2col[6] + s1v.w * w2col[7]
              + s2v.x * w2col[8] + s2v.y * w2col[9] + s2v.z * w2col[10] + s2v.w * w2col[11]
              + s3v.x * w2col[12] + s3v.y * w2col[13] + s3v.z * w2col[14] + s3v.w * w2col[15];

    float fdg = (float)dg;
    float inv = 1.0f / fmaxf(fdg, 1.0f);
    float h = fmaxf((red + fdg * b2g) * inv, 0.0f);

    // logits via 16-lane allreduce
    float c0 = h * wp0, c1 = h * wp1;
    #pragma unroll
    for (int mset = 8; mset > 0; mset >>= 1) {
        c0 += __shfl_xor(c0, mset);
        c1 += __shfl_xor(c1, mset);
    }
    float l0 = c0 + bp[0], l1 = c1 + bp[1];
    float mx = fmaxf(l0, l1);
    float e0s = __expf(l0 - mx), e1s = __expf(l1 - mx);
    float isum = 1.0f / (e0s + e1s);
    float s0 = e0s * isum, s1 = e1s * isum;

    if (g == 0) ((float2*)out_s)[n] = make_float2(s0, s1);

    // fused pooling: block-level LDS reduce over the <=2 graphs this block spans
    __shared__ float lpool[2][32];
    __shared__ int sg0;
    if (t == 0) sg0 = batch[blockIdx.x * 16];
    if (t < 64) lpool[t >> 5][t & 31] = 0.0f;
    __syncthreads();

    int gid = batch[n];
    int idx = gid - sg0;
    float p0 = s0 * h, p1 = s1 * h;
    if (idx < 2) {
        atomicAdd(&lpool[idx][g], p0);
        atomicAdd(&lpool[idx][16 + g], p1);
    } else {  // pathological tiny-graph fallback
        atomicAdd(&pooled[gid * 32 + g], p0);
        atomicAdd(&pooled[gid * 32 + 16 + g], p1);
    }
    __syncthreads();
    if (t < 32) {
        float v = lpool[0][t];
        if (v != 0.0f) atomicAdd(&pooled[sg0 * 32 + t], v);
        v = lpool[1][t];
        if (v != 0.0f) atomicAdd(&pooled[(sg0 + 1) * 32 + t], v);
    }
}

// ---------------------------------------------------------------------------
// z = pooled.reshape(G,32) @ Wz + bz
// ---------------------------------------------------------------------------
__global__ __launch_bounds__(256) void z_kernel(const float* __restrict__ pooled,
                                                const float* __restrict__ Wz,
                                                const float* __restrict__ bz,
                                                float* __restrict__ out_z) {
    int idx = blockIdx.x * 256 + threadIdx.x;
    if (idx >= N_GRAPHS * 8) return;
    int gph = idx >> 3, o = idx & 7;
    float a = bz[o];
    const float* pp = pooled + (size_t)gph * 32;
    #pragma unroll
    for (int j = 0; j < 32; ++j) a = fmaf(pp[j], Wz[j * 8 + o], a);
    out_z[idx] = a;
}

extern "C" void kernel_launch(void* const* d_in, const int* in_sizes, int n_in,
                              void* d_out, int out_size, void* d_ws, size_t ws_size,
                              hipStream_t stream) {
    const float* x    = (const float*)d_in[0];
    const float* pos  = (const float*)d_in[1];
    const float* W1   = (const float*)d_in[2];
    const float* b1   = (const float*)d_in[3];
    const float* W2   = (const float*)d_in[4];
    const float* b2   = (const float*)d_in[5];
    const float* Wp   = (const float*)d_in[6];
    const float* bp   = (const float*)d_in[7];
    const float* Wz   = (const float*)d_in[8];
    const float* bz   = (const float*)d_in[9];
    const int*   ei   = (const int*)d_in[10];
    const int*   batch= (const int*)d_in[11];
    float* out = (float*)d_out;
    float* out_z = out;                   // [1024*8]
    float* out_s = out + N_GRAPHS * 8;    // [262144*2]

    // ws (ints): gcur[NBK*16] | binned[NBK*CAP] (=srcs after passC) |
    //            startg[N] | degg[N] | pooled[1025*32] | px16[N uint4]
    int* gcur     = (int*)d_ws;
    int* binned   = gcur + NBK * 16;
    int* startg   = binned + (size_t)NBK * CAP;
    int* degg     = startg + N_NODES;
    float* pooled = (float*)(degg + N_NODES);
    uint4* px16   = (uint4*)(pooled + 1025 * 32);   // offset is 16B-aligned

    hipMemsetAsync(gcur, 0, NBK * 16 * sizeof(int), stream);
    fusedAB<<<ABLK, 256, 0, stream>>>(ei, x, pos, gcur, binned, px16, pooled);
    passC_sort<<<NBK, 256, 0, stream>>>(gcur, binned, startg, degg);
    node_gather_fused<<<N_NODES / 16, 256, 0, stream>>>(
        px16, binned, startg, degg, W1, b1, W2, b2, Wp, bp, batch, out_s, pooled);
    z_kernel<<<32, 256, 0, stream>>>(pooled, Wz, bz, out_z);
}

// Round 10
// 184.001 us; speedup vs baseline: 2.4937x; 1.0835x over previous
//
#include <hip/hip_runtime.h>
#include <hip/hip_fp16.h>
#include <math.h>

#define N_NODES 262144
#define N_EDGES 4194304
#define N_GRAPHS 1024
#define NBK 512                  // dst buckets (512 nodes each)
#define CAP 8960                 // per-bucket capacity (mean 8192 + 8.5 sigma)
#define ABLK 512                 // fusedAB blocks
#define AEPB (N_EDGES / ABLK)    // 8192 edges per block; run = 16 edges = 64B

typedef _Float16 half2v __attribute__((ext_vector_type(2)));
__device__ inline half2v u2h(unsigned u) { union { unsigned u; half2v h; } c; c.u = u; return c.h; }
__device__ inline unsigned packh2(float a, float b) {
    union { __half2 h; unsigned u; } c; c.h = __floats2half2_rn(a, b); return c.u;
}

// ---------------------------------------------------------------------------
// fusedAB: pack px16 + zero pooled + per-block bucket hist + global range
// reservation + line-dense binned scatter of (src | dstlow<<18).
// 512 buckets x 16-edge avg runs per block = full-line writes.
// ---------------------------------------------------------------------------
__global__ __launch_bounds__(256) void fusedAB(
    const int* __restrict__ ei, const float* __restrict__ x,
    const float* __restrict__ pos, int* __restrict__ gcur,
    int* __restrict__ binned, uint4* __restrict__ px16,
    float* __restrict__ pooled)
{
    __shared__ int lh[NBK];
    int t = threadIdx.x, b = blockIdx.x;

    // pack 2 nodes per thread (fp16 x4 + pos3 -> one 16B record, 4MB total)
    #pragma unroll
    for (int k = 0; k < 2; ++k) {
        int n = b * 512 + k * 256 + t;
        float4 v = ((const float4*)x)[n];
        float p0 = pos[3 * n], p1 = pos[3 * n + 1], p2 = pos[3 * n + 2];
        uint4 r;
        r.x = packh2(v.x, v.y);
        r.y = packh2(v.z, v.w);
        r.z = packh2(p0, p1);
        r.w = packh2(p2, 0.0f);
        px16[n] = r;
    }
    int pid = b * 256 + t;
    if (pid < 1025 * 32) pooled[pid] = 0.0f;

    #pragma unroll
    for (int k = 0; k < 2; ++k) lh[t + 256 * k] = 0;
    __syncthreads();

    int base = b * AEPB;
    for (int i = 0; i < AEPB / 256; ++i) {
        int d = ei[N_EDGES + base + i * 256 + t];
        atomicAdd(&lh[d >> 9], 1);
    }
    __syncthreads();
    #pragma unroll
    for (int k = 0; k < 2; ++k) {
        int kb = t + 256 * k;
        lh[kb] = atomicAdd(&gcur[kb * 16], lh[kb]);   // reserve contiguous range
    }
    __syncthreads();
    for (int i = 0; i < AEPB / 256; ++i) {
        int e = base + i * 256 + t;
        int s = ei[e];
        int d = ei[N_EDGES + e];
        int slot = atomicAdd(&lh[d >> 9], 1);
        if (slot < CAP)
            binned[(size_t)(d >> 9) * CAP + slot] = s | ((d & 511) << 18);
    }
}

// ---------------------------------------------------------------------------
// passC: per-bucket node sort, in place. 512 threads per block, one block per
// 512-node bucket. Stage bucket edges in LDS, per-node deg + 512-wide scan,
// rewrite the SAME binned region node-grouped (src-only). srcs aliases binned.
// ---------------------------------------------------------------------------
__global__ __launch_bounds__(512) void passC_sort(
    const int* __restrict__ gcur,
    int* __restrict__ binned,
    int* __restrict__ startg, int* __restrict__ degg)
{
    __shared__ int lbuf[CAP];
    __shared__ int ldeg[512], sc2[512], lcur[512];
    int t = threadIdx.x, k = blockIdx.x;
    int ebase = k * CAP;
    int cnt = gcur[k * 16];
    if (cnt > CAP) cnt = CAP;

    ldeg[t] = 0;
    __syncthreads();
    for (int i = t; i < cnt; i += 512) {
        int pk = binned[ebase + i];
        lbuf[i] = pk;
        atomicAdd(&ldeg[pk >> 18], 1);
    }
    __syncthreads();
    sc2[t] = ldeg[t];
    __syncthreads();
    for (int o = 1; o < 512; o <<= 1) {
        int u = (t >= o) ? sc2[t - o] : 0;
        __syncthreads();
        sc2[t] += u;
        __syncthreads();
    }
    int excl = sc2[t] - ldeg[t];
    int n = k * 512 + t;
    startg[n] = ebase + excl;
    degg[n] = ldeg[t];
    lcur[t] = excl;
    __syncthreads();
    for (int i = t; i < cnt; i += 512) {
        int pk = lbuf[i];
        int slot = atomicAdd(&lcur[pk >> 18], 1);
        binned[ebase + slot] = pk & 0x3FFFF;
    }
}

// ---------------------------------------------------------------------------
// Gather + edge MLP (R7-verified, byte-identical). Inner loop: 1 ds_read_b128
// per edge + 2 v_dot2_f32_f16 + exp chain. W2 applied once per node via LDS
// transpose of sumH. Fused per-graph pooling.
// ---------------------------------------------------------------------------
__global__ __launch_bounds__(256) void node_gather_fused(
    const uint4* __restrict__ px16,
    const int* __restrict__ srcs, const int* __restrict__ startg,
    const int* __restrict__ degg,
    const float* __restrict__ W1, const float* __restrict__ b1,
    const float* __restrict__ W2, const float* __restrict__ b2,
    const float* __restrict__ Wp, const float* __restrict__ bp,
    const int* __restrict__ batch,
    float* __restrict__ out_s, float* __restrict__ pooled)
{
    __shared__ uint4 sepk[16][17];   // staged edges: {x01,x23,dist,pad}
    __shared__ float smh[16][20];    // sumH transpose (padded rows)

    int t = threadIdx.x;
    int g = t & 15;
    int grp = t >> 4;
    int n = blockIdx.x * 16 + grp;

    // per-lane weights (registers)
    float w1c0 = W1[0 * 16 + g], w1c1 = W1[1 * 16 + g];
    float w1c2 = W1[2 * 16 + g], w1c3 = W1[3 * 16 + g];
    half2v wh45, wh67;
    wh45[0] = (_Float16)W1[4 * 16 + g];
    wh45[1] = (_Float16)W1[5 * 16 + g];
    wh67[0] = (_Float16)W1[6 * 16 + g];
    wh67[1] = (_Float16)W1[7 * 16 + g];
    float w1c8 = W1[8 * 16 + g];
    float b1g = b1[g], b2g = b2[g];
    float w2col[16];
    #pragma unroll
    for (int i = 0; i < 16; ++i) w2col[i] = W2[i * 16 + g];  // column g
    float wp0 = Wp[2 * g], wp1 = Wp[2 * g + 1];

    int base = startg[n];
    int dg = degg[n];

    // self record
    uint4 rn = px16[n];
    float2 f01 = __half22float2(*(__half2*)&rn.x);
    float2 f23 = __half22float2(*(__half2*)&rn.y);
    float2 f45 = __half22float2(*(__half2*)&rn.z);
    float2 f67 = __half22float2(*(__half2*)&rn.w);
    float pnx = f45.x, pny = f45.y, pnz = f67.x;
    float pre = b1g + f01.x * w1c0 + f01.y * w1c1 + f23.x * w1c2 + f23.y * w1c3;

    float sumH = 0.0f;

    // pipeline prologue
    int sC = 0;
    if (g < dg) sC = srcs[base + g];
    uint4 rC = px16[sC];
    int sN = sC;
    if (16 + g < dg) sN = srcs[base + 16 + g];

    for (int k0 = 0; k0 < dg; k0 += 16) {
        int rem = dg - k0;
        int cnt = rem < 16 ? rem : 16;
        if (g < cnt) {
            float2 e45 = __half22float2(*(__half2*)&rC.z);
            float2 e67 = __half22float2(*(__half2*)&rC.w);
            float dx = e45.x - pnx, dy = e45.y - pny, dz = e67.x - pnz;
            float dist = sqrtf(dx * dx + dy * dy + dz * dz);
            sepk[grp][g] = make_uint4(rC.x, rC.y, __float_as_uint(dist), 0u);
        }
        // issue next chunk's loads
        uint4 rNext = px16[sN];
        int sNN = sN;
        if (k0 + 32 + g < dg) sNN = srcs[base + k0 + 32 + g];
        // compute current chunk from LDS (2x unrolled to batch waits)
        int j = 0;
        for (; j + 1 < cnt; j += 2) {
            uint4 A = sepk[grp][j];
            uint4 B = sepk[grp][j + 1];
            float a = fmaf(__uint_as_float(A.z), w1c8, pre);
            a = __builtin_amdgcn_fdot2(u2h(A.x), wh45, a, false);
            a = __builtin_amdgcn_fdot2(u2h(A.y), wh67, a, false);
            sumH += a * __builtin_amdgcn_rcpf(1.0f + __expf(-a));
            float b = fmaf(__uint_as_float(B.z), w1c8, pre);
            b = __builtin_amdgcn_fdot2(u2h(B.x), wh45, b, false);
            b = __builtin_amdgcn_fdot2(u2h(B.y), wh67, b, false);
            sumH += b * __builtin_amdgcn_rcpf(1.0f + __expf(-b));
        }
        if (j < cnt) {
            uint4 A = sepk[grp][j];
            float a = fmaf(__uint_as_float(A.z), w1c8, pre);
            a = __builtin_amdgcn_fdot2(u2h(A.x), wh45, a, false);
            a = __builtin_amdgcn_fdot2(u2h(A.y), wh67, a, false);
            sumH += a * __builtin_amdgcn_rcpf(1.0f + __expf(-a));
        }
        rC = rNext;
        sN = sNN;
    }

    // LDS-transpose epilogue: lane g applies W2 column g.
    smh[grp][g] = sumH;
    float4 s0v = *(const float4*)&smh[grp][0];
    float4 s1v = *(const float4*)&smh[grp][4];
    float4 s2v = *(const float4*)&smh[grp][8];
    float4 s3v = *(const float4*)&smh[grp][12];
    float red = s0v.x * w2col[0] + s0v.y * w2col[1] + s0v.z * w2col[2] + s0v.w * w2col[3]
              + s1v.x * w2col[4] + s1v.y * w2col[5] + s1v.z * w2col[6] + s1v.w * w2col[7]
              + s2v.x * w2col[8] + s2v.y * w2col[9] + s2v.z * w2col[10] + s2v.w * w2col[11]
              + s3v.x * w2col[12] + s3v.y * w2col[13] + s3v.z * w2col[14] + s3v.w * w2col[15];

    float fdg = (float)dg;
    float inv = 1.0f / fmaxf(fdg, 1.0f);
    float h = fmaxf((red + fdg * b2g) * inv, 0.0f);

    // logits via 16-lane allreduce
    float c0 = h * wp0, c1 = h * wp1;
    #pragma unroll
    for (int mset = 8; mset > 0; mset >>= 1) {
        c0 += __shfl_xor(c0, mset);
        c1 += __shfl_xor(c1, mset);
    }
    float l0 = c0 + bp[0], l1 = c1 + bp[1];
    float mx = fmaxf(l0, l1);
    float e0s = __expf(l0 - mx), e1s = __expf(l1 - mx);
    float isum = 1.0f / (e0s + e1s);
    float s0 = e0s * isum, s1 = e1s * isum;

    if (g == 0) ((float2*)out_s)[n] = make_float2(s0, s1);

    // fused pooling: block-level LDS reduce over the <=2 graphs this block spans
    __shared__ float lpool[2][32];
    __shared__ int sg0;
    if (t == 0) sg0 = batch[blockIdx.x * 16];
    if (t < 64) lpool[t >> 5][t & 31] = 0.0f;
    __syncthreads();

    int gid = batch[n];
    int idx = gid - sg0;
    float p0 = s0 * h, p1 = s1 * h;
    if (idx < 2) {
        atomicAdd(&lpool[idx][g], p0);
        atomicAdd(&lpool[idx][16 + g], p1);
    } else {  // pathological tiny-graph fallback
        atomicAdd(&pooled[gid * 32 + g], p0);
        atomicAdd(&pooled[gid * 32 + 16 + g], p1);
    }
    __syncthreads();
    if (t < 32) {
        float v = lpool[0][t];
        if (v != 0.0f) atomicAdd(&pooled[sg0 * 32 + t], v);
        v = lpool[1][t];
        if (v != 0.0f) atomicAdd(&pooled[(sg0 + 1) * 32 + t], v);
    }
}

// ---------------------------------------------------------------------------
// z = pooled.reshape(G,32) @ Wz + bz
// ---------------------------------------------------------------------------
__global__ __launch_bounds__(256) void z_kernel(const float* __restrict__ pooled,
                                                const float* __restrict__ Wz,
                                                const float* __restrict__ bz,
                                                float* __restrict__ out_z) {
    int idx = blockIdx.x * 256 + threadIdx.x;
    if (idx >= N_GRAPHS * 8) return;
    int gph = idx >> 3, o = idx & 7;
    float a = bz[o];
    const float* pp = pooled + (size_t)gph * 32;
    #pragma unroll
    for (int j = 0; j < 32; ++j) a = fmaf(pp[j], Wz[j * 8 + o], a);
    out_z[idx] = a;
}

extern "C" void kernel_launch(void* const* d_in, const int* in_sizes, int n_in,
                              void* d_out, int out_size, void* d_ws, size_t ws_size,
                              hipStream_t stream) {
    const float* x    = (const float*)d_in[0];
    const float* pos  = (const float*)d_in[1];
    const float* W1   = (const float*)d_in[2];
    const float* b1   = (const float*)d_in[3];
    const float* W2   = (const float*)d_in[4];
    const float* b2   = (const float*)d_in[5];
    const float* Wp   = (const float*)d_in[6];
    const float* bp   = (const float*)d_in[7];
    const float* Wz   = (const float*)d_in[8];
    const float* bz   = (const float*)d_in[9];
    const int*   ei   = (const int*)d_in[10];
    const int*   batch= (const int*)d_in[11];
    float* out = (float*)d_out;
    float* out_z = out;                   // [1024*8]
    float* out_s = out + N_GRAPHS * 8;    // [262144*2]

    // ws (ints): gcur[NBK*16] | binned[NBK*CAP] (=srcs after passC) |
    //            startg[N] | degg[N] | pooled[1025*32] | px16[N uint4]
    int* gcur     = (int*)d_ws;
    int* binned   = gcur + NBK * 16;
    int* startg   = binned + (size_t)NBK * CAP;
    int* degg     = startg + N_NODES;
    float* pooled = (float*)(degg + N_NODES);
    uint4* px16   = (uint4*)(pooled + 1025 * 32);   // offset is 16B-aligned

    hipMemsetAsync(gcur, 0, NBK * 16 * sizeof(int), stream);
    fusedAB<<<ABLK, 256, 0, stream>>>(ei, x, pos, gcur, binned, px16, pooled);
    passC_sort<<<NBK, 512, 0, stream>>>(gcur, binned, startg, degg);
    node_gather_fused<<<N_NODES / 16, 256, 0, stream>>>(
        px16, binned, startg, degg, W1, b1, W2, b2, Wp, bp, batch, out_s, pooled);
    z_kernel<<<32, 256, 0, stream>>>(pooled, Wz, bz, out_z);
}